// Round 3
// baseline (4498.289 us; speedup 1.0000x reference)
//
#include <hip/hip_runtime.h>
#include <cstddef>

#define NB 32
#define NS 64
#define NH 768
#define NSEG_ (NB*NS)      // 2048
#define NIN 816
#define G4 3072
#define HOR_ 24
#define LBLK 192           // persistent blocks (<= 256 CUs -> all co-resident)

// workspace offsets (floats)
#define OFF_X      0
#define SZ_X       (NSEG_*NIN)
#define OFF_MEAN   (OFF_X + SZ_X)
#define SZ_MEAN    (NSEG_*NH)
#define OFF_TMP    (OFF_MEAN + SZ_MEAN)
#define OFF_HSEQ0  (OFF_TMP + SZ_MEAN)
#define OFF_HSEQ1  (OFF_HSEQ0 + SZ_MEAN)
#define OFF_XG     (OFF_HSEQ1 + SZ_MEAN)
#define SZ_XG      (NSEG_*G4)
#define OFF_HBUF   (OFF_XG + SZ_XG)
#define SZ_HBUF    (2*NB*NH)
#define OFF_CTR    (OFF_HBUF + SZ_HBUF)   // 16 floats: barrier counter lives here

// ---------------------------------------------------------------------------
// Segment mean: encs [65536,768] -> mean [2048,768]
// ---------------------------------------------------------------------------
__global__ __launch_bounds__(192) void seg_mean_kernel(
    const float* __restrict__ encs, float* __restrict__ mean) {
  const int s = blockIdx.x;
  const int t = threadIdx.x;              // 0..191, 4 cols each
  const float4* base = (const float4*)(encs + (size_t)s * 32 * NH);
  float4 a = {0.f, 0.f, 0.f, 0.f};
  #pragma unroll 4
  for (int r = 0; r < 32; ++r) {
    float4 v = base[(size_t)r * (NH / 4) + t];
    a.x += v.x; a.y += v.y; a.z += v.z; a.w += v.w;
  }
  const float inv = 1.f / 32.f;
  float4 o = {a.x * inv, a.y * inv, a.z * inv, a.w * inv};
  ((float4*)mean)[(size_t)s * (NH / 4) + t] = o;
}

// ---------------------------------------------------------------------------
// C[M,N] = A[M,K] @ W[N,K]^T + bias1[n] + bias2[n]   (fp32, 64x64 tile)
// ---------------------------------------------------------------------------
__global__ __launch_bounds__(256) void gemm_nt(
    const float* __restrict__ A, const float* __restrict__ W,
    const float* __restrict__ bias1, const float* __restrict__ bias2,
    float* __restrict__ C, int M, int N, int K) {
  __shared__ float As[16][65];
  __shared__ float Ws[16][65];
  const int tid = threadIdx.x;
  const int bm = blockIdx.y, bn = blockIdx.x;
  const int tm = tid >> 4, tn = tid & 15;
  const int lr  = tid >> 2;
  const int lk4 = (tid & 3) << 2;
  float acc[4][4] = {};
  const float* Ap = A + (size_t)bm * 64 * K;
  const float* Wp = W + (size_t)bn * 64 * K;
  for (int k0 = 0; k0 < K; k0 += 16) {
    float4 av = *(const float4*)(Ap + (size_t)lr * K + k0 + lk4);
    float4 wv = *(const float4*)(Wp + (size_t)lr * K + k0 + lk4);
    __syncthreads();
    As[lk4 + 0][lr] = av.x; As[lk4 + 1][lr] = av.y;
    As[lk4 + 2][lr] = av.z; As[lk4 + 3][lr] = av.w;
    Ws[lk4 + 0][lr] = wv.x; Ws[lk4 + 1][lr] = wv.y;
    Ws[lk4 + 2][lr] = wv.z; Ws[lk4 + 3][lr] = wv.w;
    __syncthreads();
    #pragma unroll
    for (int kk = 0; kk < 16; ++kk) {
      float a0 = As[kk][tm * 4 + 0], a1 = As[kk][tm * 4 + 1];
      float a2 = As[kk][tm * 4 + 2], a3 = As[kk][tm * 4 + 3];
      float w0 = Ws[kk][tn * 4 + 0], w1 = Ws[kk][tn * 4 + 1];
      float w2 = Ws[kk][tn * 4 + 2], w3 = Ws[kk][tn * 4 + 3];
      acc[0][0] += a0 * w0; acc[0][1] += a0 * w1; acc[0][2] += a0 * w2; acc[0][3] += a0 * w3;
      acc[1][0] += a1 * w0; acc[1][1] += a1 * w1; acc[1][2] += a1 * w2; acc[1][3] += a1 * w3;
      acc[2][0] += a2 * w0; acc[2][1] += a2 * w1; acc[2][2] += a2 * w2; acc[2][3] += a2 * w3;
      acc[3][0] += a3 * w0; acc[3][1] += a3 * w1; acc[3][2] += a3 * w2; acc[3][3] += a3 * w3;
    }
  }
  const int gn = bn * 64 + tn * 4;
  float b4[4];
  #pragma unroll
  for (int j = 0; j < 4; ++j) {
    float bb = 0.f;
    if (bias1) bb += bias1[gn + j];
    if (bias2) bb += bias2[gn + j];
    b4[j] = bb;
  }
  #pragma unroll
  for (int i = 0; i < 4; ++i) {
    float* Cp = C + (size_t)(bm * 64 + tm * 4 + i) * N + gn;
    #pragma unroll
    for (int j = 0; j < 4; ++j) Cp[j] = acc[i][j] + b4[j];
  }
}

// ---------------------------------------------------------------------------
// x[s*32+b][0:816] = concat(z[b,s], cond[b,s], encoded[b*64+s])
// ---------------------------------------------------------------------------
__global__ __launch_bounds__(256) void build_x_kernel(
    const float* __restrict__ z, const float* __restrict__ cond,
    const float* __restrict__ enc, float* __restrict__ x) {
  const int idx = blockIdx.x * 256 + threadIdx.x;
  const int r = idx / NIN, c = idx % NIN;
  const int s = r >> 5, b = r & 31;
  const int bs = b * NS + s;
  float v;
  if (c < 32)      v = z[bs * 32 + c];
  else if (c < 48) v = cond[bs * 16 + (c - 32)];
  else             v = enc[(size_t)bs * NH + (c - 48)];
  x[idx] = v;
}

// ---------------------------------------------------------------------------
// Persistent LSTM layer, 192 blocks x 256 threads, NORMAL launch (no coop).
// Grid-wide sync via monotonic atomic counter in ws (zeroed each call by
// hipMemsetAsync -> deterministic under graph replay).  Block owns 4 hidden
// units x 4 gates = 16 Whh rows, held in registers for all 64 steps.
// h staged global->LDS in two 16-batch halves; k-sliced dot + shfl reduce.
// c state lives in registers of the pointwise threads (tid<128).
// ---------------------------------------------------------------------------
#define HP 772
__global__ __launch_bounds__(256) void lstm_persist(
    const float* __restrict__ xg,    // [64*32][3072], row = t*32+b (biases folded)
    const float* __restrict__ Whh,   // [3072][768]
    float* __restrict__ hpp,         // [2][32][768], zeroed before launch
    float* __restrict__ hseq,        // [2048][768], row = t*32+b
    unsigned* ctr) {                 // zeroed before launch
  __shared__ float h_lds[16][HP];
  __shared__ float gs[16][33];
  const int tid = threadIdx.x;
  const int s  = tid & 15;           // k-slice
  const int r8 = (tid >> 4) & 7;     // row-pair selector
  const int b2 = tid >> 7;           // batch parity (wave-uniform)
  const int jl = r8 & 3;
  const int g0 = r8 >> 2;            // gates g0 and g0+2
  const int j  = blockIdx.x * 4 + jl;
  const size_t row0 = (size_t)(g0)     * NH + j;
  const size_t row1 = (size_t)(g0 + 2) * NH + j;
  float4 w0[12], w1[12];
  #pragma unroll
  for (int m = 0; m < 12; ++m) {
    w0[m] = *(const float4*)(Whh + row0 * NH + (s * 4 + m * 64));
    w1[m] = *(const float4*)(Whh + row1 * NH + (s * 4 + m * 64));
  }
  // pointwise mapping (tid < 128): cell (jpw, bpw), c kept in register
  const int bpw = tid & 31, lpw = (tid >> 5) & 3;
  const int jpw = blockIdx.x * 4 + lpw;
  float c_reg = 0.f;

  for (int t = 0; t < NS; ++t) {
    const float* hprev = hpp + (size_t)(t & 1) * (NB * NH);
    float*       hnext = hpp + (size_t)((t + 1) & 1) * (NB * NH);
    // prefetch xg for this step's pointwise (latency hides under the dots)
    float xgv0 = 0.f, xgv1 = 0.f, xgv2 = 0.f, xgv3 = 0.f;
    if (tid < 128) {
      const float* xr = xg + (size_t)(t * NB + bpw) * G4 + jpw;
      xgv0 = xr[0]; xgv1 = xr[NH]; xgv2 = xr[2 * NH]; xgv3 = xr[3 * NH];
    }
    #pragma unroll
    for (int half = 0; half < 2; ++half) {
      for (int i = tid; i < 16 * (NH / 4); i += 256) {
        const int bl = i / (NH / 4), k4 = i - bl * (NH / 4);
        float4 v = *(const float4*)(hprev + (size_t)(half * 16 + bl) * NH + k4 * 4);
        *(float4*)(&h_lds[bl][k4 * 4]) = v;
      }
      __syncthreads();
      for (int i = 0; i < 8; ++i) {
        const int b = 2 * i + b2;     // local batch 0..15
        float a0 = 0.f, a1 = 0.f;
        #pragma unroll
        for (int m = 0; m < 12; ++m) {
          float4 hv = *(const float4*)(&h_lds[b][s * 4 + m * 64]);
          a0 += w0[m].x * hv.x + w0[m].y * hv.y + w0[m].z * hv.z + w0[m].w * hv.w;
          a1 += w1[m].x * hv.x + w1[m].y * hv.y + w1[m].z * hv.z + w1[m].w * hv.w;
        }
        #pragma unroll
        for (int mk = 1; mk < 16; mk <<= 1) {
          a0 += __shfl_xor(a0, mk);
          a1 += __shfl_xor(a1, mk);
        }
        if (s == 0) {
          const int gb = half * 16 + b;
          gs[r8][gb]     = a0;
          gs[r8 + 8][gb] = a1;
        }
      }
      __syncthreads();   // dots done; h_lds safe to overwrite next half
    }
    if (tid < 128) {
      const float iv = gs[0 * 4 + lpw][bpw] + xgv0;
      const float fv = gs[1 * 4 + lpw][bpw] + xgv1;
      const float gv = gs[2 * 4 + lpw][bpw] + xgv2;
      const float ov = gs[3 * 4 + lpw][bpw] + xgv3;
      const float si = 1.f / (1.f + expf(-iv));
      const float sf = 1.f / (1.f + expf(-fv));
      const float so = 1.f / (1.f + expf(-ov));
      c_reg = sf * c_reg + si * tanhf(gv);
      const float hnew = so * tanhf(c_reg);
      hnext[(size_t)bpw * NH + jpw] = hnew;
      hseq[(size_t)(t * NB + bpw) * NH + jpw] = hnew;
    }
    // ---- grid barrier (skip after final step; kernel end is the release) ----
    if (t < NS - 1) {
      __syncthreads();                 // all writes of this block issued
      if (tid == 0) {
        __threadfence();               // release: my block's writes -> agent
        atomicAdd(ctr, 1u);            // device-scope by default
        const unsigned target = (unsigned)(t + 1) * LBLK;
        while (__hip_atomic_load(ctr, __ATOMIC_RELAXED,
                                 __HIP_MEMORY_SCOPE_AGENT) < target)
          __builtin_amdgcn_s_sleep(2);
        __threadfence();               // acquire: invalidate stale L1/L2 lines
      }
      __syncthreads();
    }
  }
}

// ---------------------------------------------------------------------------
// preds[b*24+s] = dot(h1seq[s*32+b], Wout) + bout
// ---------------------------------------------------------------------------
__global__ __launch_bounds__(64) void head_kernel(
    const float* __restrict__ hseq1, const float* __restrict__ Wout,
    const float* __restrict__ bout, float* __restrict__ preds) {
  const int o = blockIdx.x;
  const int b = o / HOR_, s = o % HOR_;
  const int l = threadIdx.x;
  const float* h = hseq1 + (size_t)(s * NB + b) * NH;
  float acc = 0.f;
  #pragma unroll
  for (int k = l; k < NH; k += 64) acc += h[k] * Wout[k];
  #pragma unroll
  for (int m = 32; m; m >>= 1) acc += __shfl_xor(acc, m);
  if (l == 0) preds[o] = acc + bout[0];
}

// ---------------------------------------------------------------------------
extern "C" void kernel_launch(void* const* d_in, const int* in_sizes, int n_in,
                              void* d_out, int out_size, void* d_ws, size_t ws_size,
                              hipStream_t stream) {
  const float* z    = (const float*)d_in[0];
  const float* cond = (const float*)d_in[1];
  const float* encs = (const float*)d_in[2];
  const float* W1   = (const float*)d_in[4];
  const float* b1   = (const float*)d_in[5];
  const float* W2   = (const float*)d_in[6];
  const float* b2   = (const float*)d_in[7];
  const float* Wih0 = (const float*)d_in[8];
  const float* Whh0 = (const float*)d_in[9];
  const float* bih0 = (const float*)d_in[10];
  const float* bhh0 = (const float*)d_in[11];
  const float* Wih1 = (const float*)d_in[12];
  const float* Whh1 = (const float*)d_in[13];
  const float* bih1 = (const float*)d_in[14];
  const float* bhh1 = (const float*)d_in[15];
  const float* Wout = (const float*)d_in[16];
  const float* bout = (const float*)d_in[17];

  float* out     = (float*)d_out;
  float* preds   = out;
  float* enc_out = out + NB * HOR_;

  float* ws    = (float*)d_ws;
  float* xb    = ws + OFF_X;
  float* mean  = ws + OFF_MEAN;
  float* tmp   = ws + OFF_TMP;
  float* hseq0 = ws + OFF_HSEQ0;
  float* hseq1 = ws + OFF_HSEQ1;
  float* xg    = ws + OFF_XG;
  float* hbuf  = ws + OFF_HBUF;
  unsigned* ctr = (unsigned*)(ws + OFF_CTR);

  // 1. segment mean (filter and mean are linear and commute -> pool first)
  seg_mean_kernel<<<NSEG_, 192, 0, stream>>>(encs, mean);
  // 2. encoded = (mean @ W1^T + b1) @ W2^T + b2 -> straight into d_out
  gemm_nt<<<dim3(NH / 64, NSEG_ / 64), 256, 0, stream>>>(
      mean, W1, b1, nullptr, tmp, NSEG_, NH, NH);
  gemm_nt<<<dim3(NH / 64, NSEG_ / 64), 256, 0, stream>>>(
      tmp, W2, b2, nullptr, enc_out, NSEG_, NH, NH);
  // 3. x = concat(z, cond, encoded), time-major rows (s*32+b)
  build_x_kernel<<<(NSEG_ * NIN) / 256, 256, 0, stream>>>(z, cond, enc_out, xb);
  // 4. layer-0 input gates (biases folded in)
  gemm_nt<<<dim3(G4 / 64, NSEG_ / 64), 256, 0, stream>>>(
      xb, Wih0, bih0, bhh0, xg, NSEG_, G4, NIN);
  // 5. layer-0 recurrence (persistent kernel, own grid barrier in ws)
  hipMemsetAsync(hbuf, 0, (size_t)(SZ_HBUF + 16) * sizeof(float), stream);
  lstm_persist<<<LBLK, 256, 0, stream>>>(xg, Whh0, hbuf, hseq0, ctr);
  // 6. layer-1 input gates
  gemm_nt<<<dim3(G4 / 64, NSEG_ / 64), 256, 0, stream>>>(
      hseq0, Wih1, bih1, bhh1, xg, NSEG_, G4, NH);
  // 7. layer-1 recurrence
  hipMemsetAsync(hbuf, 0, (size_t)(SZ_HBUF + 16) * sizeof(float), stream);
  lstm_persist<<<LBLK, 256, 0, stream>>>(xg, Whh1, hbuf, hseq1, ctr);
  // 8. head
  head_kernel<<<NB * HOR_, 64, 0, stream>>>(hseq1, Wout, bout, preds);
}

// Round 4
// 4302.258 us; speedup vs baseline: 1.0456x; 1.0456x over previous
//
#include <hip/hip_runtime.h>
#include <cstddef>

#define NB 32
#define NS 64
#define NH 768
#define NSEG_ (NB*NS)      // 2048
#define NIN 816
#define G4 3072
#define HOR_ 24
#define LBLK 192           // persistent blocks (<= 256 CUs -> all co-resident)

// workspace offsets (floats)
#define OFF_X      0
#define SZ_X       (NSEG_*NIN)
#define OFF_MEAN   (OFF_X + SZ_X)
#define SZ_MEAN    (NSEG_*NH)
#define OFF_TMP    (OFF_MEAN + SZ_MEAN)
#define OFF_HSEQ0  (OFF_TMP + SZ_MEAN)
#define OFF_HSEQ1  (OFF_HSEQ0 + SZ_MEAN)
#define OFF_XG     (OFF_HSEQ1 + SZ_MEAN)
#define SZ_XG      (NSEG_*G4)
#define OFF_HBUF   (OFF_XG + SZ_XG)
#define SZ_HBUF    (2*NB*NH)
#define OFF_CTR    (OFF_HBUF + SZ_HBUF)   // 8 counters spread over 8 cache lines

// ---------------------------------------------------------------------------
// Segment mean: encs [65536,768] -> mean [2048,768]
// ---------------------------------------------------------------------------
__global__ __launch_bounds__(192) void seg_mean_kernel(
    const float* __restrict__ encs, float* __restrict__ mean) {
  const int s = blockIdx.x;
  const int t = threadIdx.x;              // 0..191, 4 cols each
  const float4* base = (const float4*)(encs + (size_t)s * 32 * NH);
  float4 a = {0.f, 0.f, 0.f, 0.f};
  #pragma unroll 4
  for (int r = 0; r < 32; ++r) {
    float4 v = base[(size_t)r * (NH / 4) + t];
    a.x += v.x; a.y += v.y; a.z += v.z; a.w += v.w;
  }
  const float inv = 1.f / 32.f;
  float4 o = {a.x * inv, a.y * inv, a.z * inv, a.w * inv};
  ((float4*)mean)[(size_t)s * (NH / 4) + t] = o;
}

// ---------------------------------------------------------------------------
// C[M,N] = A[M,K] @ W[N,K]^T + bias1[n] + bias2[n]   (fp32, 64x64 tile)
// ---------------------------------------------------------------------------
__global__ __launch_bounds__(256) void gemm_nt(
    const float* __restrict__ A, const float* __restrict__ W,
    const float* __restrict__ bias1, const float* __restrict__ bias2,
    float* __restrict__ C, int M, int N, int K) {
  __shared__ float As[16][65];
  __shared__ float Ws[16][65];
  const int tid = threadIdx.x;
  const int bm = blockIdx.y, bn = blockIdx.x;
  const int tm = tid >> 4, tn = tid & 15;
  const int lr  = tid >> 2;
  const int lk4 = (tid & 3) << 2;
  float acc[4][4] = {};
  const float* Ap = A + (size_t)bm * 64 * K;
  const float* Wp = W + (size_t)bn * 64 * K;
  for (int k0 = 0; k0 < K; k0 += 16) {
    float4 av = *(const float4*)(Ap + (size_t)lr * K + k0 + lk4);
    float4 wv = *(const float4*)(Wp + (size_t)lr * K + k0 + lk4);
    __syncthreads();
    As[lk4 + 0][lr] = av.x; As[lk4 + 1][lr] = av.y;
    As[lk4 + 2][lr] = av.z; As[lk4 + 3][lr] = av.w;
    Ws[lk4 + 0][lr] = wv.x; Ws[lk4 + 1][lr] = wv.y;
    Ws[lk4 + 2][lr] = wv.z; Ws[lk4 + 3][lr] = wv.w;
    __syncthreads();
    #pragma unroll
    for (int kk = 0; kk < 16; ++kk) {
      float a0 = As[kk][tm * 4 + 0], a1 = As[kk][tm * 4 + 1];
      float a2 = As[kk][tm * 4 + 2], a3 = As[kk][tm * 4 + 3];
      float w0 = Ws[kk][tn * 4 + 0], w1 = Ws[kk][tn * 4 + 1];
      float w2 = Ws[kk][tn * 4 + 2], w3 = Ws[kk][tn * 4 + 3];
      acc[0][0] += a0 * w0; acc[0][1] += a0 * w1; acc[0][2] += a0 * w2; acc[0][3] += a0 * w3;
      acc[1][0] += a1 * w0; acc[1][1] += a1 * w1; acc[1][2] += a1 * w2; acc[1][3] += a1 * w3;
      acc[2][0] += a2 * w0; acc[2][1] += a2 * w1; acc[2][2] += a2 * w2; acc[2][3] += a2 * w3;
      acc[3][0] += a3 * w0; acc[3][1] += a3 * w1; acc[3][2] += a3 * w2; acc[3][3] += a3 * w3;
    }
  }
  const int gn = bn * 64 + tn * 4;
  float b4[4];
  #pragma unroll
  for (int j = 0; j < 4; ++j) {
    float bb = 0.f;
    if (bias1) bb += bias1[gn + j];
    if (bias2) bb += bias2[gn + j];
    b4[j] = bb;
  }
  #pragma unroll
  for (int i = 0; i < 4; ++i) {
    float* Cp = C + (size_t)(bm * 64 + tm * 4 + i) * N + gn;
    #pragma unroll
    for (int j = 0; j < 4; ++j) Cp[j] = acc[i][j] + b4[j];
  }
}

// ---------------------------------------------------------------------------
// x[s*32+b][0:816] = concat(z[b,s], cond[b,s], encoded[b*64+s])
// ---------------------------------------------------------------------------
__global__ __launch_bounds__(256) void build_x_kernel(
    const float* __restrict__ z, const float* __restrict__ cond,
    const float* __restrict__ enc, float* __restrict__ x) {
  const int idx = blockIdx.x * 256 + threadIdx.x;
  const int r = idx / NIN, c = idx % NIN;
  const int s = r >> 5, b = r & 31;
  const int bs = b * NS + s;
  float v;
  if (c < 32)      v = z[bs * 32 + c];
  else if (c < 48) v = cond[bs * 16 + (c - 32)];
  else             v = enc[(size_t)bs * NH + (c - 48)];
  x[idx] = v;
}

// ---------------------------------------------------------------------------
// Persistent LSTM layer, 192 blocks x 256 threads, normal launch.
// waves_per_eu(1,1): max 1 wave/SIMD -> 512-VGPR budget so the 24 float4 of
// Whh stay RESIDENT across all 64 steps (round-3 failure: VGPR=68 meant the
// compiler remat'd the weight loads inside the loop -> 9.4 MB/step refetch).
// Grid barrier: 8 cache-line-spread counters (24 arrivals each), 8 parallel
// pollers; fence discipline identical to the round-3 passing version.
// ---------------------------------------------------------------------------
#define HP 772
__global__ __launch_bounds__(256)
__attribute__((amdgpu_waves_per_eu(1, 1)))
void lstm_persist(
    const float* __restrict__ xg,    // [64*32][3072], row = t*32+b (biases folded)
    const float* __restrict__ Whh,   // [3072][768]
    float* __restrict__ hpp,         // [2][32][768], zeroed before launch
    float* __restrict__ hseq,        // [2048][768], row = t*32+b
    unsigned* ctr) {                 // 8 counters at stride 16 u32, zeroed
  __shared__ float h_lds[16][HP];
  __shared__ float gs[16][33];
  const int tid = threadIdx.x;
  const int s  = tid & 15;           // k-slice
  const int r8 = (tid >> 4) & 7;     // row-pair selector
  const int b2 = tid >> 7;           // batch parity (wave-uniform)
  const int jl = r8 & 3;
  const int g0 = r8 >> 2;            // gates g0 and g0+2
  const int j  = blockIdx.x * 4 + jl;
  const size_t row0 = (size_t)(g0)     * NH + j;
  const size_t row1 = (size_t)(g0 + 2) * NH + j;
  float4 w0[12], w1[12];
  #pragma unroll
  for (int m = 0; m < 12; ++m) {
    w0[m] = *(const float4*)(Whh + row0 * NH + (s * 4 + m * 64));
    w1[m] = *(const float4*)(Whh + row1 * NH + (s * 4 + m * 64));
  }
  // pointwise mapping (tid < 128): cell (jpw, bpw), c kept in register
  const int bpw = tid & 31, lpw = (tid >> 5) & 3;
  const int jpw = blockIdx.x * 4 + lpw;
  float c_reg = 0.f;

  for (int t = 0; t < NS; ++t) {
    const float* hprev = hpp + (size_t)(t & 1) * (NB * NH);
    float*       hnext = hpp + (size_t)((t + 1) & 1) * (NB * NH);
    // prefetch xg for this step's pointwise (latency hides under the dots)
    float xgv0 = 0.f, xgv1 = 0.f, xgv2 = 0.f, xgv3 = 0.f;
    if (tid < 128) {
      const float* xr = xg + (size_t)(t * NB + bpw) * G4 + jpw;
      xgv0 = xr[0]; xgv1 = xr[NH]; xgv2 = xr[2 * NH]; xgv3 = xr[3 * NH];
    }
    #pragma unroll
    for (int half = 0; half < 2; ++half) {
      for (int i = tid; i < 16 * (NH / 4); i += 256) {
        const int bl = i / (NH / 4), k4 = i - bl * (NH / 4);
        float4 v = *(const float4*)(hprev + (size_t)(half * 16 + bl) * NH + k4 * 4);
        *(float4*)(&h_lds[bl][k4 * 4]) = v;
      }
      __syncthreads();
      for (int i = 0; i < 8; ++i) {
        const int b = 2 * i + b2;     // local batch 0..15
        float a0 = 0.f, a1 = 0.f;
        #pragma unroll
        for (int m = 0; m < 12; ++m) {
          float4 hv = *(const float4*)(&h_lds[b][s * 4 + m * 64]);
          a0 += w0[m].x * hv.x + w0[m].y * hv.y + w0[m].z * hv.z + w0[m].w * hv.w;
          a1 += w1[m].x * hv.x + w1[m].y * hv.y + w1[m].z * hv.z + w1[m].w * hv.w;
        }
        #pragma unroll
        for (int mk = 1; mk < 16; mk <<= 1) {
          a0 += __shfl_xor(a0, mk);
          a1 += __shfl_xor(a1, mk);
        }
        if (s == 0) {
          const int gb = half * 16 + b;
          gs[r8][gb]     = a0;
          gs[r8 + 8][gb] = a1;
        }
      }
      __syncthreads();   // dots done; h_lds safe to overwrite next half
    }
    if (tid < 128) {
      const float iv = gs[0 * 4 + lpw][bpw] + xgv0;
      const float fv = gs[1 * 4 + lpw][bpw] + xgv1;
      const float gv = gs[2 * 4 + lpw][bpw] + xgv2;
      const float ov = gs[3 * 4 + lpw][bpw] + xgv3;
      const float si = 1.f / (1.f + expf(-iv));
      const float sf = 1.f / (1.f + expf(-fv));
      const float so = 1.f / (1.f + expf(-ov));
      c_reg = sf * c_reg + si * tanhf(gv);
      const float hnew = so * tanhf(c_reg);
      hnext[(size_t)bpw * NH + jpw] = hnew;
      hseq[(size_t)(t * NB + bpw) * NH + jpw] = hnew;
    }
    // ---- grid barrier (skip after final step; kernel end is the release) ----
    if (t < NS - 1) {
      __syncthreads();                 // all writes of this block issued
      if (tid == 0) {
        __threadfence();               // release: my block's writes -> agent
        atomicAdd(&ctr[(blockIdx.x & 7) * 16], 1u);
      }
      if (tid < 8) {
        const unsigned target = (unsigned)(t + 1) * (LBLK / 8);
        while (__hip_atomic_load(&ctr[tid * 16], __ATOMIC_RELAXED,
                                 __HIP_MEMORY_SCOPE_AGENT) < target)
          __builtin_amdgcn_s_sleep(2);
        __threadfence();               // acquire: invalidate stale caches
      }
      __syncthreads();
    }
  }
}

// ---------------------------------------------------------------------------
// preds[b*24+s] = dot(h1seq[s*32+b], Wout) + bout
// ---------------------------------------------------------------------------
__global__ __launch_bounds__(64) void head_kernel(
    const float* __restrict__ hseq1, const float* __restrict__ Wout,
    const float* __restrict__ bout, float* __restrict__ preds) {
  const int o = blockIdx.x;
  const int b = o / HOR_, s = o % HOR_;
  const int l = threadIdx.x;
  const float* h = hseq1 + (size_t)(s * NB + b) * NH;
  float acc = 0.f;
  #pragma unroll
  for (int k = l; k < NH; k += 64) acc += h[k] * Wout[k];
  #pragma unroll
  for (int m = 32; m; m >>= 1) acc += __shfl_xor(acc, m);
  if (l == 0) preds[o] = acc + bout[0];
}

// ---------------------------------------------------------------------------
extern "C" void kernel_launch(void* const* d_in, const int* in_sizes, int n_in,
                              void* d_out, int out_size, void* d_ws, size_t ws_size,
                              hipStream_t stream) {
  const float* z    = (const float*)d_in[0];
  const float* cond = (const float*)d_in[1];
  const float* encs = (const float*)d_in[2];
  const float* W1   = (const float*)d_in[4];
  const float* b1   = (const float*)d_in[5];
  const float* W2   = (const float*)d_in[6];
  const float* b2   = (const float*)d_in[7];
  const float* Wih0 = (const float*)d_in[8];
  const float* Whh0 = (const float*)d_in[9];
  const float* bih0 = (const float*)d_in[10];
  const float* bhh0 = (const float*)d_in[11];
  const float* Wih1 = (const float*)d_in[12];
  const float* Whh1 = (const float*)d_in[13];
  const float* bih1 = (const float*)d_in[14];
  const float* bhh1 = (const float*)d_in[15];
  const float* Wout = (const float*)d_in[16];
  const float* bout = (const float*)d_in[17];

  float* out     = (float*)d_out;
  float* preds   = out;
  float* enc_out = out + NB * HOR_;

  float* ws    = (float*)d_ws;
  float* xb    = ws + OFF_X;
  float* mean  = ws + OFF_MEAN;
  float* tmp   = ws + OFF_TMP;
  float* hseq0 = ws + OFF_HSEQ0;
  float* hseq1 = ws + OFF_HSEQ1;
  float* xg    = ws + OFF_XG;
  float* hbuf  = ws + OFF_HBUF;
  unsigned* ctr = (unsigned*)(ws + OFF_CTR);

  // 1. segment mean (filter and mean are linear and commute -> pool first)
  seg_mean_kernel<<<NSEG_, 192, 0, stream>>>(encs, mean);
  // 2. encoded = (mean @ W1^T + b1) @ W2^T + b2 -> straight into d_out
  gemm_nt<<<dim3(NH / 64, NSEG_ / 64), 256, 0, stream>>>(
      mean, W1, b1, nullptr, tmp, NSEG_, NH, NH);
  gemm_nt<<<dim3(NH / 64, NSEG_ / 64), 256, 0, stream>>>(
      tmp, W2, b2, nullptr, enc_out, NSEG_, NH, NH);
  // 3. x = concat(z, cond, encoded), time-major rows (s*32+b)
  build_x_kernel<<<(NSEG_ * NIN) / 256, 256, 0, stream>>>(z, cond, enc_out, xb);
  // 4. layer-0 input gates (biases folded in)
  gemm_nt<<<dim3(G4 / 64, NSEG_ / 64), 256, 0, stream>>>(
      xb, Wih0, bih0, bhh0, xg, NSEG_, G4, NIN);
  // 5. layer-0 recurrence (persistent kernel, own grid barrier in ws)
  hipMemsetAsync(hbuf, 0, (size_t)(SZ_HBUF + 128) * sizeof(float), stream);
  lstm_persist<<<LBLK, 256, 0, stream>>>(xg, Whh0, hbuf, hseq0, ctr);
  // 6. layer-1 input gates
  gemm_nt<<<dim3(G4 / 64, NSEG_ / 64), 256, 0, stream>>>(
      hseq0, Wih1, bih1, bhh1, xg, NSEG_, G4, NH);
  // 7. layer-1 recurrence
  hipMemsetAsync(hbuf, 0, (size_t)(SZ_HBUF + 128) * sizeof(float), stream);
  lstm_persist<<<LBLK, 256, 0, stream>>>(xg, Whh1, hbuf, hseq1, ctr);
  // 8. head
  head_kernel<<<NB * HOR_, 64, 0, stream>>>(hseq1, Wout, bout, preds);
}

// Round 5
// 3699.332 us; speedup vs baseline: 1.2160x; 1.1630x over previous
//
#include <hip/hip_runtime.h>
#include <cstddef>

#define NB 32
#define NS 64
#define NH 768
#define NSEG_ (NB*NS)      // 2048
#define NIN 816
#define G4 3072
#define HOR_ 24
#define LBLK 192           // persistent blocks (<= 256 CUs -> all co-resident)

// workspace offsets (floats)
#define OFF_X      0
#define SZ_X       (NSEG_*NIN)
#define OFF_MEAN   (OFF_X + SZ_X)
#define SZ_MEAN    (NSEG_*NH)
#define OFF_TMP    (OFF_MEAN + SZ_MEAN)
#define OFF_HSEQ0  (OFF_TMP + SZ_MEAN)
#define OFF_HSEQ1  (OFF_HSEQ0 + SZ_MEAN)
#define OFF_XG     (OFF_HSEQ1 + SZ_MEAN)
#define SZ_XG      (NSEG_*G4)
#define OFF_HBUF   (OFF_XG + SZ_XG)
#define SZ_HBUF    (2*NB*NH)
#define OFF_CTR    (OFF_HBUF + SZ_HBUF)   // 8 counters spread over 8 cache lines

// ---- coherent (agent-scope) access helpers: these ride the coherent path, ----
// ---- so NO cache-wide fences (buffer_wbl2/inv) are needed for visibility. ----
__device__ __forceinline__ float2 coh_load_f2(const float* p) {
  unsigned long long v = __hip_atomic_load((const unsigned long long*)p,
                                           __ATOMIC_RELAXED,
                                           __HIP_MEMORY_SCOPE_AGENT);
  union { unsigned long long u; float2 f; } c; c.u = v; return c.f;
}
__device__ __forceinline__ void coh_store_f(float* p, float v) {
  union { float f; unsigned u; } c; c.f = v;
  __hip_atomic_store((unsigned*)p, c.u, __ATOMIC_RELAXED,
                     __HIP_MEMORY_SCOPE_AGENT);
}

// ---------------------------------------------------------------------------
// Segment mean: encs [65536,768] -> mean [2048,768]
// ---------------------------------------------------------------------------
__global__ __launch_bounds__(192) void seg_mean_kernel(
    const float* __restrict__ encs, float* __restrict__ mean) {
  const int s = blockIdx.x;
  const int t = threadIdx.x;              // 0..191, 4 cols each
  const float4* base = (const float4*)(encs + (size_t)s * 32 * NH);
  float4 a = {0.f, 0.f, 0.f, 0.f};
  #pragma unroll 4
  for (int r = 0; r < 32; ++r) {
    float4 v = base[(size_t)r * (NH / 4) + t];
    a.x += v.x; a.y += v.y; a.z += v.z; a.w += v.w;
  }
  const float inv = 1.f / 32.f;
  float4 o = {a.x * inv, a.y * inv, a.z * inv, a.w * inv};
  ((float4*)mean)[(size_t)s * (NH / 4) + t] = o;
}

// ---------------------------------------------------------------------------
// C[M,N] = A[M,K] @ W[N,K]^T + bias1[n] + bias2[n]   (fp32, 64x64 tile)
// ---------------------------------------------------------------------------
__global__ __launch_bounds__(256) void gemm_nt(
    const float* __restrict__ A, const float* __restrict__ W,
    const float* __restrict__ bias1, const float* __restrict__ bias2,
    float* __restrict__ C, int M, int N, int K) {
  __shared__ float As[16][65];
  __shared__ float Ws[16][65];
  const int tid = threadIdx.x;
  const int bm = blockIdx.y, bn = blockIdx.x;
  const int tm = tid >> 4, tn = tid & 15;
  const int lr  = tid >> 2;
  const int lk4 = (tid & 3) << 2;
  float acc[4][4] = {};
  const float* Ap = A + (size_t)bm * 64 * K;
  const float* Wp = W + (size_t)bn * 64 * K;
  for (int k0 = 0; k0 < K; k0 += 16) {
    float4 av = *(const float4*)(Ap + (size_t)lr * K + k0 + lk4);
    float4 wv = *(const float4*)(Wp + (size_t)lr * K + k0 + lk4);
    __syncthreads();
    As[lk4 + 0][lr] = av.x; As[lk4 + 1][lr] = av.y;
    As[lk4 + 2][lr] = av.z; As[lk4 + 3][lr] = av.w;
    Ws[lk4 + 0][lr] = wv.x; Ws[lk4 + 1][lr] = wv.y;
    Ws[lk4 + 2][lr] = wv.z; Ws[lk4 + 3][lr] = wv.w;
    __syncthreads();
    #pragma unroll
    for (int kk = 0; kk < 16; ++kk) {
      float a0 = As[kk][tm * 4 + 0], a1 = As[kk][tm * 4 + 1];
      float a2 = As[kk][tm * 4 + 2], a3 = As[kk][tm * 4 + 3];
      float w0 = Ws[kk][tn * 4 + 0], w1 = Ws[kk][tn * 4 + 1];
      float w2 = Ws[kk][tn * 4 + 2], w3 = Ws[kk][tn * 4 + 3];
      acc[0][0] += a0 * w0; acc[0][1] += a0 * w1; acc[0][2] += a0 * w2; acc[0][3] += a0 * w3;
      acc[1][0] += a1 * w0; acc[1][1] += a1 * w1; acc[1][2] += a1 * w2; acc[1][3] += a1 * w3;
      acc[2][0] += a2 * w0; acc[2][1] += a2 * w1; acc[2][2] += a2 * w2; acc[2][3] += a2 * w3;
      acc[3][0] += a3 * w0; acc[3][1] += a3 * w1; acc[3][2] += a3 * w2; acc[3][3] += a3 * w3;
    }
  }
  const int gn = bn * 64 + tn * 4;
  float b4[4];
  #pragma unroll
  for (int j = 0; j < 4; ++j) {
    float bb = 0.f;
    if (bias1) bb += bias1[gn + j];
    if (bias2) bb += bias2[gn + j];
    b4[j] = bb;
  }
  #pragma unroll
  for (int i = 0; i < 4; ++i) {
    float* Cp = C + (size_t)(bm * 64 + tm * 4 + i) * N + gn;
    #pragma unroll
    for (int j = 0; j < 4; ++j) Cp[j] = acc[i][j] + b4[j];
  }
}

// ---------------------------------------------------------------------------
// x[s*32+b][0:816] = concat(z[b,s], cond[b,s], encoded[b*64+s])
// ---------------------------------------------------------------------------
__global__ __launch_bounds__(256) void build_x_kernel(
    const float* __restrict__ z, const float* __restrict__ cond,
    const float* __restrict__ enc, float* __restrict__ x) {
  const int idx = blockIdx.x * 256 + threadIdx.x;
  const int r = idx / NIN, c = idx % NIN;
  const int s = r >> 5, b = r & 31;
  const int bs = b * NS + s;
  float v;
  if (c < 32)      v = z[bs * 32 + c];
  else if (c < 48) v = cond[bs * 16 + (c - 32)];
  else             v = enc[(size_t)bs * NH + (c - 48)];
  x[idx] = v;
}

// ---------------------------------------------------------------------------
// Persistent LSTM layer, 192 blocks x 256 threads, normal launch.
// Cross-block data (hnext + barrier counters) moves EXCLUSIVELY through
// agent-scope atomics (coherent path) -> no __threadfence / buffer_wbl2 /
// buffer_inv in the step loop (round-4 post-mortem: those fences were ~26 of
// 29 us/step).  Ordering: __syncthreads() drains vmcnt before arrival.
// Block owns 4 hidden units x 4 gates = 16 Whh rows, resident in registers.
// ---------------------------------------------------------------------------
#define HP 772
__global__ __launch_bounds__(256)
__attribute__((amdgpu_waves_per_eu(1, 1)))
void lstm_persist(
    const float* __restrict__ xg,    // [64*32][3072], row = t*32+b (biases folded)
    const float* __restrict__ Whh,   // [3072][768]
    float* __restrict__ hpp,         // [2][32][768], zeroed before launch
    float* __restrict__ hseq,        // [2048][768], row = t*32+b
    unsigned* ctr) {                 // 8 counters at stride 16 u32, zeroed
  __shared__ float h_lds[16][HP];
  __shared__ float gs[16][33];
  const int tid = threadIdx.x;
  const int s  = tid & 15;           // k-slice
  const int r8 = (tid >> 4) & 7;     // row-pair selector
  const int b2 = tid >> 7;           // batch parity (wave-uniform)
  const int jl = r8 & 3;
  const int g0 = r8 >> 2;            // gates g0 and g0+2
  const int j  = blockIdx.x * 4 + jl;
  const size_t row0 = (size_t)(g0)     * NH + j;
  const size_t row1 = (size_t)(g0 + 2) * NH + j;
  float4 w0[12], w1[12];
  #pragma unroll
  for (int m = 0; m < 12; ++m) {
    w0[m] = *(const float4*)(Whh + row0 * NH + (s * 4 + m * 64));
    w1[m] = *(const float4*)(Whh + row1 * NH + (s * 4 + m * 64));
  }
  // pointwise mapping (tid < 128): cell (jpw, bpw), c kept in register
  const int bpw = tid & 31, lpw = (tid >> 5) & 3;
  const int jpw = blockIdx.x * 4 + lpw;
  float c_reg = 0.f;

  for (int t = 0; t < NS; ++t) {
    const float* hprev = hpp + (size_t)(t & 1) * (NB * NH);
    float*       hnext = hpp + (size_t)((t + 1) & 1) * (NB * NH);
    // prefetch xg for this step's pointwise (latency hides under the dots)
    float xgv0 = 0.f, xgv1 = 0.f, xgv2 = 0.f, xgv3 = 0.f;
    if (tid < 128) {
      const float* xr = xg + (size_t)(t * NB + bpw) * G4 + jpw;
      xgv0 = xr[0]; xgv1 = xr[NH]; xgv2 = xr[2 * NH]; xgv3 = xr[3 * NH];
    }
    #pragma unroll
    for (int half = 0; half < 2; ++half) {
      // stage h for batches [half*16, half*16+16) via coherent 8B loads
      for (int i = tid; i < 16 * (NH / 2); i += 256) {
        const int bl = i / (NH / 2), k2 = i - bl * (NH / 2);
        float2 v = coh_load_f2(hprev + (size_t)(half * 16 + bl) * NH + k2 * 2);
        *(float2*)(&h_lds[bl][k2 * 2]) = v;
      }
      __syncthreads();
      for (int i = 0; i < 8; ++i) {
        const int b = 2 * i + b2;     // local batch 0..15
        float a0 = 0.f, a1 = 0.f;
        #pragma unroll
        for (int m = 0; m < 12; ++m) {
          float4 hv = *(const float4*)(&h_lds[b][s * 4 + m * 64]);
          a0 += w0[m].x * hv.x + w0[m].y * hv.y + w0[m].z * hv.z + w0[m].w * hv.w;
          a1 += w1[m].x * hv.x + w1[m].y * hv.y + w1[m].z * hv.z + w1[m].w * hv.w;
        }
        #pragma unroll
        for (int mk = 1; mk < 16; mk <<= 1) {
          a0 += __shfl_xor(a0, mk);
          a1 += __shfl_xor(a1, mk);
        }
        if (s == 0) {
          const int gb = half * 16 + b;
          gs[r8][gb]     = a0;
          gs[r8 + 8][gb] = a1;
        }
      }
      __syncthreads();   // dots done; h_lds safe to overwrite next half
    }
    if (tid < 128) {
      const float iv = gs[0 * 4 + lpw][bpw] + xgv0;
      const float fv = gs[1 * 4 + lpw][bpw] + xgv1;
      const float gv = gs[2 * 4 + lpw][bpw] + xgv2;
      const float ov = gs[3 * 4 + lpw][bpw] + xgv3;
      const float si = 1.f / (1.f + expf(-iv));
      const float sf = 1.f / (1.f + expf(-fv));
      const float so = 1.f / (1.f + expf(-ov));
      c_reg = sf * c_reg + si * tanhf(gv);
      const float hnew = so * tanhf(c_reg);
      coh_store_f(&hnext[(size_t)bpw * NH + jpw], hnew);      // coherent
      hseq[(size_t)(t * NB + bpw) * NH + jpw] = hnew;         // plain (next kernel)
    }
    // ---- grid barrier: arrival after syncthreads (which drains vmcnt) ----
    if (t < NS - 1) {
      __syncthreads();                 // all waves' stores retired
      if (tid == 0) {
        asm volatile("s_waitcnt vmcnt(0)" ::: "memory");
        __hip_atomic_fetch_add(&ctr[(blockIdx.x & 7) * 16], 1u,
                               __ATOMIC_RELAXED, __HIP_MEMORY_SCOPE_AGENT);
      }
      if (tid < 8) {
        const unsigned target = (unsigned)(t + 1) * (LBLK / 8);
        while (__hip_atomic_load(&ctr[tid * 16], __ATOMIC_RELAXED,
                                 __HIP_MEMORY_SCOPE_AGENT) < target)
          __builtin_amdgcn_s_sleep(2);
      }
      __syncthreads();
    }
  }
}

// ---------------------------------------------------------------------------
// preds[b*24+s] = dot(h1seq[s*32+b], Wout) + bout
// ---------------------------------------------------------------------------
__global__ __launch_bounds__(64) void head_kernel(
    const float* __restrict__ hseq1, const float* __restrict__ Wout,
    const float* __restrict__ bout, float* __restrict__ preds) {
  const int o = blockIdx.x;
  const int b = o / HOR_, s = o % HOR_;
  const int l = threadIdx.x;
  const float* h = hseq1 + (size_t)(s * NB + b) * NH;
  float acc = 0.f;
  #pragma unroll
  for (int k = l; k < NH; k += 64) acc += h[k] * Wout[k];
  #pragma unroll
  for (int m = 32; m; m >>= 1) acc += __shfl_xor(acc, m);
  if (l == 0) preds[o] = acc + bout[0];
}

// ---------------------------------------------------------------------------
extern "C" void kernel_launch(void* const* d_in, const int* in_sizes, int n_in,
                              void* d_out, int out_size, void* d_ws, size_t ws_size,
                              hipStream_t stream) {
  const float* z    = (const float*)d_in[0];
  const float* cond = (const float*)d_in[1];
  const float* encs = (const float*)d_in[2];
  const float* W1   = (const float*)d_in[4];
  const float* b1   = (const float*)d_in[5];
  const float* W2   = (const float*)d_in[6];
  const float* b2   = (const float*)d_in[7];
  const float* Wih0 = (const float*)d_in[8];
  const float* Whh0 = (const float*)d_in[9];
  const float* bih0 = (const float*)d_in[10];
  const float* bhh0 = (const float*)d_in[11];
  const float* Wih1 = (const float*)d_in[12];
  const float* Whh1 = (const float*)d_in[13];
  const float* bih1 = (const float*)d_in[14];
  const float* bhh1 = (const float*)d_in[15];
  const float* Wout = (const float*)d_in[16];
  const float* bout = (const float*)d_in[17];

  float* out     = (float*)d_out;
  float* preds   = out;
  float* enc_out = out + NB * HOR_;

  float* ws    = (float*)d_ws;
  float* xb    = ws + OFF_X;
  float* mean  = ws + OFF_MEAN;
  float* tmp   = ws + OFF_TMP;
  float* hseq0 = ws + OFF_HSEQ0;
  float* hseq1 = ws + OFF_HSEQ1;
  float* xg    = ws + OFF_XG;
  float* hbuf  = ws + OFF_HBUF;
  unsigned* ctr = (unsigned*)(ws + OFF_CTR);

  // 1. segment mean (filter and mean are linear and commute -> pool first)
  seg_mean_kernel<<<NSEG_, 192, 0, stream>>>(encs, mean);
  // 2. encoded = (mean @ W1^T + b1) @ W2^T + b2 -> straight into d_out
  gemm_nt<<<dim3(NH / 64, NSEG_ / 64), 256, 0, stream>>>(
      mean, W1, b1, nullptr, tmp, NSEG_, NH, NH);
  gemm_nt<<<dim3(NH / 64, NSEG_ / 64), 256, 0, stream>>>(
      tmp, W2, b2, nullptr, enc_out, NSEG_, NH, NH);
  // 3. x = concat(z, cond, encoded), time-major rows (s*32+b)
  build_x_kernel<<<(NSEG_ * NIN) / 256, 256, 0, stream>>>(z, cond, enc_out, xb);
  // 4. layer-0 input gates (biases folded in)
  gemm_nt<<<dim3(G4 / 64, NSEG_ / 64), 256, 0, stream>>>(
      xb, Wih0, bih0, bhh0, xg, NSEG_, G4, NIN);
  // 5. layer-0 recurrence (persistent kernel, own grid barrier in ws)
  hipMemsetAsync(hbuf, 0, (size_t)(SZ_HBUF + 128) * sizeof(float), stream);
  lstm_persist<<<LBLK, 256, 0, stream>>>(xg, Whh0, hbuf, hseq0, ctr);
  // 6. layer-1 input gates
  gemm_nt<<<dim3(G4 / 64, NSEG_ / 64), 256, 0, stream>>>(
      hseq0, Wih1, bih1, bhh1, xg, NSEG_, G4, NH);
  // 7. layer-1 recurrence
  hipMemsetAsync(hbuf, 0, (size_t)(SZ_HBUF + 128) * sizeof(float), stream);
  lstm_persist<<<LBLK, 256, 0, stream>>>(xg, Whh1, hbuf, hseq1, ctr);
  // 8. head
  head_kernel<<<NB * HOR_, 64, 0, stream>>>(hseq1, Wout, bout, preds);
}

// Round 6
// 2554.445 us; speedup vs baseline: 1.7610x; 1.4482x over previous
//
#include <hip/hip_runtime.h>
#include <cstddef>

#define NB 32
#define NS 64
#define NH 768
#define NSEG_ (NB*NS)      // 2048
#define NIN 816
#define G4 3072
#define HOR_ 24
#define LBLK 96            // persistent blocks (96 CUs, 1 block/CU)
#define LTHR 512           // 8 waves/block = 2 waves per EU

// workspace offsets (floats)
#define OFF_X      0
#define SZ_X       (NSEG_*NIN)
#define OFF_MEAN   (OFF_X + SZ_X)
#define SZ_MEAN    (NSEG_*NH)
#define OFF_TMP    (OFF_MEAN + SZ_MEAN)
#define OFF_HSEQ0  (OFF_TMP + SZ_MEAN)
#define OFF_HSEQ1  (OFF_HSEQ0 + SZ_MEAN)
#define OFF_XG     (OFF_HSEQ1 + SZ_MEAN)
#define SZ_XG      (NSEG_*G4)
#define OFF_HZERO  (OFF_XG + SZ_XG)
#define SZ_HZERO   (NB*NH)
#define OFF_CTR    (OFF_HZERO + SZ_HZERO)   // 8 counters spread over 8 lines

// agent-scope write-through store: value lands at the coherence point, so a
// later first-touch cached read (or later kernel) sees it without any
// cache-wide fence.
__device__ __forceinline__ void coh_store_f(float* p, float v) {
  union { float f; unsigned u; } c; c.f = v;
  __hip_atomic_store((unsigned*)p, c.u, __ATOMIC_RELAXED,
                     __HIP_MEMORY_SCOPE_AGENT);
}

// ---------------------------------------------------------------------------
// Segment mean: encs [65536,768] -> mean [2048,768]
// ---------------------------------------------------------------------------
__global__ __launch_bounds__(192) void seg_mean_kernel(
    const float* __restrict__ encs, float* __restrict__ mean) {
  const int s = blockIdx.x;
  const int t = threadIdx.x;              // 0..191, 4 cols each
  const float4* base = (const float4*)(encs + (size_t)s * 32 * NH);
  float4 a = {0.f, 0.f, 0.f, 0.f};
  #pragma unroll 4
  for (int r = 0; r < 32; ++r) {
    float4 v = base[(size_t)r * (NH / 4) + t];
    a.x += v.x; a.y += v.y; a.z += v.z; a.w += v.w;
  }
  const float inv = 1.f / 32.f;
  float4 o = {a.x * inv, a.y * inv, a.z * inv, a.w * inv};
  ((float4*)mean)[(size_t)s * (NH / 4) + t] = o;
}

// ---------------------------------------------------------------------------
// C[M,N] = A[M,K] @ W[N,K]^T + bias1[n] + bias2[n]   (fp32, 64x64 tile)
// ---------------------------------------------------------------------------
__global__ __launch_bounds__(256) void gemm_nt(
    const float* __restrict__ A, const float* __restrict__ W,
    const float* __restrict__ bias1, const float* __restrict__ bias2,
    float* __restrict__ C, int M, int N, int K) {
  __shared__ float As[16][65];
  __shared__ float Ws[16][65];
  const int tid = threadIdx.x;
  const int bm = blockIdx.y, bn = blockIdx.x;
  const int tm = tid >> 4, tn = tid & 15;
  const int lr  = tid >> 2;
  const int lk4 = (tid & 3) << 2;
  float acc[4][4] = {};
  const float* Ap = A + (size_t)bm * 64 * K;
  const float* Wp = W + (size_t)bn * 64 * K;
  for (int k0 = 0; k0 < K; k0 += 16) {
    float4 av = *(const float4*)(Ap + (size_t)lr * K + k0 + lk4);
    float4 wv = *(const float4*)(Wp + (size_t)lr * K + k0 + lk4);
    __syncthreads();
    As[lk4 + 0][lr] = av.x; As[lk4 + 1][lr] = av.y;
    As[lk4 + 2][lr] = av.z; As[lk4 + 3][lr] = av.w;
    Ws[lk4 + 0][lr] = wv.x; Ws[lk4 + 1][lr] = wv.y;
    Ws[lk4 + 2][lr] = wv.z; Ws[lk4 + 3][lr] = wv.w;
    __syncthreads();
    #pragma unroll
    for (int kk = 0; kk < 16; ++kk) {
      float a0 = As[kk][tm * 4 + 0], a1 = As[kk][tm * 4 + 1];
      float a2 = As[kk][tm * 4 + 2], a3 = As[kk][tm * 4 + 3];
      float w0 = Ws[kk][tn * 4 + 0], w1 = Ws[kk][tn * 4 + 1];
      float w2 = Ws[kk][tn * 4 + 2], w3 = Ws[kk][tn * 4 + 3];
      acc[0][0] += a0 * w0; acc[0][1] += a0 * w1; acc[0][2] += a0 * w2; acc[0][3] += a0 * w3;
      acc[1][0] += a1 * w0; acc[1][1] += a1 * w1; acc[1][2] += a1 * w2; acc[1][3] += a1 * w3;
      acc[2][0] += a2 * w0; acc[2][1] += a2 * w1; acc[2][2] += a2 * w2; acc[2][3] += a2 * w3;
      acc[3][0] += a3 * w0; acc[3][1] += a3 * w1; acc[3][2] += a3 * w2; acc[3][3] += a3 * w3;
    }
  }
  const int gn = bn * 64 + tn * 4;
  float b4[4];
  #pragma unroll
  for (int j = 0; j < 4; ++j) {
    float bb = 0.f;
    if (bias1) bb += bias1[gn + j];
    if (bias2) bb += bias2[gn + j];
    b4[j] = bb;
  }
  #pragma unroll
  for (int i = 0; i < 4; ++i) {
    float* Cp = C + (size_t)(bm * 64 + tm * 4 + i) * N + gn;
    #pragma unroll
    for (int j = 0; j < 4; ++j) Cp[j] = acc[i][j] + b4[j];
  }
}

// ---------------------------------------------------------------------------
// x[s*32+b][0:816] = concat(z[b,s], cond[b,s], encoded[b*64+s])
// ---------------------------------------------------------------------------
__global__ __launch_bounds__(256) void build_x_kernel(
    const float* __restrict__ z, const float* __restrict__ cond,
    const float* __restrict__ enc, float* __restrict__ x) {
  const int idx = blockIdx.x * 256 + threadIdx.x;
  const int r = idx / NIN, c = idx % NIN;
  const int s = r >> 5, b = r & 31;
  const int bs = b * NS + s;
  float v;
  if (c < 32)      v = z[bs * 32 + c];
  else if (c < 48) v = cond[bs * 16 + (c - 32)];
  else             v = enc[(size_t)bs * NH + (c - 48)];
  x[idx] = v;
}

// ---------------------------------------------------------------------------
// Persistent LSTM layer, 96 blocks x 512 threads.
// h "rotates" through hseq itself: step t writes hseq rows [t*32,(t+1)*32)
// via agent-scope WRITE-THROUGH stores (98 KB/step total); step t+1 reads
// that slice with PLAIN CACHED float4 loads -- legal because every line is
// first-touched after its write within this kernel (dispatch begins with an
// acquire/invalidate), so no stale copies can exist.  No fences, no atomic
// loads in the loop (round-5 bottleneck: 2.4M 8B atomic loads/step).
// Block owns 8 hidden units x 4 gates = 32 Whh rows, resident in registers
// (24 float4/thread).  Thread (s=tid&15: k-slice, r=(tid>>4)&15: rows r and
// r+16, b2=tid>>8: batch parity).  waves_per_eu(2,2): 8 waves = 2/EU exactly,
// 256-VGPR budget keeps weights resident.
// ---------------------------------------------------------------------------
#define HP 772
__global__ __launch_bounds__(LTHR)
__attribute__((amdgpu_waves_per_eu(2, 2)))
void lstm_persist(
    const float* __restrict__ xg,    // [64*32][3072], row = t*32+b (biases folded)
    const float* __restrict__ Whh,   // [3072][768]
    const float* __restrict__ hzero, // [32][768] zeros (step-0 input)
    float* __restrict__ hseq,        // [2048][768], row = t*32+b
    unsigned* ctr) {                 // 8 counters at stride 16 u32, zeroed
  __shared__ float h_lds[16][HP];
  __shared__ float gs[32][33];
  const int tid = threadIdx.x;
  const int s  = tid & 15;           // k-slice (48 k each)
  const int r  = (tid >> 4) & 15;    // local rows r (gates 0/1) and r+16 (2/3)
  const int b2 = tid >> 8;           // batch parity (wave-uniform)
  const int g0 = r >> 3;             // 0 or 1
  const int jl = r & 7;
  const int j  = blockIdx.x * 8 + jl;
  const size_t row0 = (size_t)(g0)     * NH + j;   // gate g0
  const size_t row1 = (size_t)(g0 + 2) * NH + j;   // gate g0+2
  float4 w0[12], w1[12];
  #pragma unroll
  for (int m = 0; m < 12; ++m) {
    w0[m] = *(const float4*)(Whh + row0 * NH + (s * 4 + m * 64));
    w1[m] = *(const float4*)(Whh + row1 * NH + (s * 4 + m * 64));
  }
  // pointwise mapping (tid < 256): cell (jpw, bpw), c kept in register
  const int bpw = tid & 31, lpw = (tid >> 5) & 7;
  const int jpw = blockIdx.x * 8 + lpw;
  float c_reg = 0.f;

  for (int t = 0; t < NS; ++t) {
    const float* hRead = (t == 0) ? hzero
                                  : hseq + (size_t)(t - 1) * NB * NH;
    // prefetch xg for this step's pointwise (latency hides under the dots)
    float xgv0 = 0.f, xgv1 = 0.f, xgv2 = 0.f, xgv3 = 0.f;
    if (tid < 256) {
      const float* xr = xg + (size_t)(t * NB + bpw) * G4 + jpw;
      xgv0 = xr[0]; xgv1 = xr[NH]; xgv2 = xr[2 * NH]; xgv3 = xr[3 * NH];
    }
    #pragma unroll
    for (int half = 0; half < 2; ++half) {
      // stage h for batches [half*16, half*16+16): plain cached float4 loads
      for (int i = tid; i < 16 * (NH / 4); i += LTHR) {
        const int bl = i / (NH / 4), k4 = i - bl * (NH / 4);
        float4 v = *(const float4*)(hRead + (size_t)(half * 16 + bl) * NH + k4 * 4);
        *(float4*)(&h_lds[bl][k4 * 4]) = v;
      }
      __syncthreads();
      for (int i = 0; i < 8; ++i) {
        const int b = 2 * i + b2;     // local batch 0..15
        float a0 = 0.f, a1 = 0.f;
        #pragma unroll
        for (int m = 0; m < 12; ++m) {
          float4 hv = *(const float4*)(&h_lds[b][s * 4 + m * 64]);
          a0 += w0[m].x * hv.x + w0[m].y * hv.y + w0[m].z * hv.z + w0[m].w * hv.w;
          a1 += w1[m].x * hv.x + w1[m].y * hv.y + w1[m].z * hv.z + w1[m].w * hv.w;
        }
        #pragma unroll
        for (int mk = 1; mk < 16; mk <<= 1) {
          a0 += __shfl_xor(a0, mk);
          a1 += __shfl_xor(a1, mk);
        }
        if (s == 0) {
          const int gb = half * 16 + b;
          gs[r][gb]      = a0;
          gs[r + 16][gb] = a1;
        }
      }
      __syncthreads();   // dots done; h_lds safe to overwrite next half
    }
    if (tid < 256) {
      const float iv = gs[0  + lpw][bpw] + xgv0;
      const float fv = gs[8  + lpw][bpw] + xgv1;
      const float gv = gs[16 + lpw][bpw] + xgv2;
      const float ov = gs[24 + lpw][bpw] + xgv3;
      const float si = 1.f / (1.f + expf(-iv));
      const float sf = 1.f / (1.f + expf(-fv));
      const float so = 1.f / (1.f + expf(-ov));
      c_reg = sf * c_reg + si * tanhf(gv);
      const float hnew = so * tanhf(c_reg);
      // single write-through store publishes h for step t+1 AND hseq output
      coh_store_f(&hseq[(size_t)(t * NB + bpw) * NH + jpw], hnew);
    }
    // ---- grid barrier ----
    if (t < NS - 1) {
      __syncthreads();                 // compiler drains vmcnt before barrier
      if (tid == 0) {
        asm volatile("s_waitcnt vmcnt(0)" ::: "memory");
        __hip_atomic_fetch_add(&ctr[(blockIdx.x & 7) * 16], 1u,
                               __ATOMIC_RELAXED, __HIP_MEMORY_SCOPE_AGENT);
      }
      if (tid < 8) {
        const unsigned target = (unsigned)(t + 1) * (LBLK / 8);
        while (__hip_atomic_load(&ctr[tid * 16], __ATOMIC_RELAXED,
                                 __HIP_MEMORY_SCOPE_AGENT) < target)
          __builtin_amdgcn_s_sleep(2);
      }
      __syncthreads();
    }
  }
}

// ---------------------------------------------------------------------------
// preds[b*24+s] = dot(h1seq[s*32+b], Wout) + bout
// ---------------------------------------------------------------------------
__global__ __launch_bounds__(64) void head_kernel(
    const float* __restrict__ hseq1, const float* __restrict__ Wout,
    const float* __restrict__ bout, float* __restrict__ preds) {
  const int o = blockIdx.x;
  const int b = o / HOR_, s = o % HOR_;
  const int l = threadIdx.x;
  const float* h = hseq1 + (size_t)(s * NB + b) * NH;
  float acc = 0.f;
  #pragma unroll
  for (int k = l; k < NH; k += 64) acc += h[k] * Wout[k];
  #pragma unroll
  for (int m = 32; m; m >>= 1) acc += __shfl_xor(acc, m);
  if (l == 0) preds[o] = acc + bout[0];
}

// ---------------------------------------------------------------------------
extern "C" void kernel_launch(void* const* d_in, const int* in_sizes, int n_in,
                              void* d_out, int out_size, void* d_ws, size_t ws_size,
                              hipStream_t stream) {
  const float* z    = (const float*)d_in[0];
  const float* cond = (const float*)d_in[1];
  const float* encs = (const float*)d_in[2];
  const float* W1   = (const float*)d_in[4];
  const float* b1   = (const float*)d_in[5];
  const float* W2   = (const float*)d_in[6];
  const float* b2   = (const float*)d_in[7];
  const float* Wih0 = (const float*)d_in[8];
  const float* Whh0 = (const float*)d_in[9];
  const float* bih0 = (const float*)d_in[10];
  const float* bhh0 = (const float*)d_in[11];
  const float* Wih1 = (const float*)d_in[12];
  const float* Whh1 = (const float*)d_in[13];
  const float* bih1 = (const float*)d_in[14];
  const float* bhh1 = (const float*)d_in[15];
  const float* Wout = (const float*)d_in[16];
  const float* bout = (const float*)d_in[17];

  float* out     = (float*)d_out;
  float* preds   = out;
  float* enc_out = out + NB * HOR_;

  float* ws    = (float*)d_ws;
  float* xb    = ws + OFF_X;
  float* mean  = ws + OFF_MEAN;
  float* tmp   = ws + OFF_TMP;
  float* hseq0 = ws + OFF_HSEQ0;
  float* hseq1 = ws + OFF_HSEQ1;
  float* xg    = ws + OFF_XG;
  float* hzero = ws + OFF_HZERO;
  unsigned* ctr = (unsigned*)(ws + OFF_CTR);

  // 1. segment mean (filter and mean are linear and commute -> pool first)
  seg_mean_kernel<<<NSEG_, 192, 0, stream>>>(encs, mean);
  // 2. encoded = (mean @ W1^T + b1) @ W2^T + b2 -> straight into d_out
  gemm_nt<<<dim3(NH / 64, NSEG_ / 64), 256, 0, stream>>>(
      mean, W1, b1, nullptr, tmp, NSEG_, NH, NH);
  gemm_nt<<<dim3(NH / 64, NSEG_ / 64), 256, 0, stream>>>(
      tmp, W2, b2, nullptr, enc_out, NSEG_, NH, NH);
  // 3. x = concat(z, cond, encoded), time-major rows (s*32+b)
  build_x_kernel<<<(NSEG_ * NIN) / 256, 256, 0, stream>>>(z, cond, enc_out, xb);
  // 4. layer-0 input gates (biases folded in)
  gemm_nt<<<dim3(G4 / 64, NSEG_ / 64), 256, 0, stream>>>(
      xb, Wih0, bih0, bhh0, xg, NSEG_, G4, NIN);
  // 5. layer-0 recurrence (persistent kernel, h rotates through hseq0)
  hipMemsetAsync(hzero, 0, (size_t)(SZ_HZERO + 128) * sizeof(float), stream);
  lstm_persist<<<LBLK, LTHR, 0, stream>>>(xg, Whh0, hzero, hseq0, ctr);
  // 6. layer-1 input gates
  gemm_nt<<<dim3(G4 / 64, NSEG_ / 64), 256, 0, stream>>>(
      hseq0, Wih1, bih1, bhh1, xg, NSEG_, G4, NH);
  // 7. layer-1 recurrence
  hipMemsetAsync(hzero, 0, (size_t)(SZ_HZERO + 128) * sizeof(float), stream);
  lstm_persist<<<LBLK, LTHR, 0, stream>>>(xg, Whh1, hzero, hseq1, ctr);
  // 8. head
  head_kernel<<<NB * HOR_, 64, 0, stream>>>(hseq1, Wout, bout, preds);
}